// Round 5
// baseline (236.449 us; speedup 1.0000x reference)
//
#include <hip/hip_runtime.h>
#include <hip/hip_bf16.h>

#define B_ 16
#define N_ 8192
#define C_ 512
#define H_ 8
#define HD_ 64
#define CH_ 32
#define TILE_R 16

// ws float layout:
//   [0, 512)          qfull (cls@Wq * scale)
//   [512, 4608)       qk[h][c]  (8 x 512)
//   [4608, 4736)      Linv[b][h]  (16 x 8)
//   [4736, 70272)     aa[b][h][c] unnormalized weighted sums (16 x 8 x 512)
//   [70272, 86656)    pp[half][b][o] partial pooled (2 x 16 x 512)
//   [86656, ...)      partials: per (b,chunk): { l[8], acc[8*512] } stride 4104
#define WS_QK   512
#define WS_LINV 4608
#define WS_AA   4736
#define WS_PP   70272
#define WS_PART 86656

// ---------------- K1: qfull = cls @ Wq * HD^-0.5 ----------------
__global__ void k_qfull(const float* __restrict__ cls, const float* __restrict__ Wq,
                        float* __restrict__ ws) {
    __shared__ float red[256];
    int t = threadIdx.x;
    int o = blockIdx.x * 64 + (t & 63);
    int q = t >> 6;  // 0..3
    float p = 0.f;
    for (int c = q * 128; c < q * 128 + 128; ++c)
        p += cls[c] * Wq[c * C_ + o];
    red[t] = p;
    __syncthreads();
    if (t < 64) {
        float s = red[t] + red[t + 64] + red[t + 128] + red[t + 192];
        ws[o] = s * 0.125f;  // HD^-0.5 = 1/8
    }
}

// ---------------- K2: qk[h][c] = sum_d Wk[c, h*64+d] * qfull[h*64+d] ----------------
__global__ void k_qk(const float* __restrict__ Wk, float* __restrict__ ws) {
    __shared__ float wrow[8 * 520];  // 8 rows of Wk, padded stride
    __shared__ float qf[512];
    int t = threadIdx.x;
    int c0 = blockIdx.x * 8;
    int r = t >> 5;             // 8 rows, 32 threads each
    int col = (t & 31) * 16;    // 16 floats per thread
    const float4* src = (const float4*)(Wk + (size_t)(c0 + r) * C_ + col);
    float4* dst = (float4*)(&wrow[r * 520 + col]);
    dst[0] = src[0]; dst[1] = src[1]; dst[2] = src[2]; dst[3] = src[3];
    if (t < 128) ((float4*)qf)[t] = ((const float4*)ws)[t];
    __syncthreads();
    if (t < 64) {
        int h = t >> 3, cc = t & 7;
        const float* wr = &wrow[cc * 520 + h * 64];
        const float* qh = &qf[h * 64];
        float s = 0.f;
#pragma unroll
        for (int d = 0; d < 64; ++d) s += wr[d] * qh[d];
        ws[WS_QK + h * C_ + c0 + cc] = s;
    }
}

// ---------------- K3: main streaming pass over x (LDS-staged, round 5) ----------------
// Theory: R1-R4 all spilled (qr64+acc64+prefetch>=32 -> 190-290 VGPR live).
// Fix: stage 16-row tiles of x in LDS (double-buffered, 1 barrier/tile);
// head-split waves (qr/acc 32+32) both read the SAME staged bytes, so HBM
// traffic stays 1x (R4's mistake). Stage regs 32, unroll-2 compute -> ~140 VGPR.
//   wave w: head group g=w>>1 (heads 4g..4g+3), row parity par=w&1.
//   Per lane cols [4L,4L+4) and [256+4L,..). Folded butterfly over 4 heads
//   (6 shuffles/row), mapping verified in R4 (passed).
__global__ __launch_bounds__(256) void k_main(const float* __restrict__ x,
                                              const float* __restrict__ ws,
                                              float* __restrict__ part, int CH) {
    __shared__ float xt[2][TILE_R * C_];  // 64 KB, double buffer
    __shared__ float sl[8];

    int blk = blockIdx.x;
    int b = blk / CH, chunk = blk % CH;
    int lane = threadIdx.x & 63, wave = threadIdx.x >> 6;
    int par = wave & 1;      // row parity this wave computes
    int g = wave >> 1;       // head group
    int rpb = N_ / CH;       // rows per block (256 at CH=32)
    int nt = rpb / TILE_R;   // tiles per block (16)
    int n0 = chunk * rpb;

    const float* xp = x + ((size_t)b * N_ + n0) * C_;
    int lo = 4 * lane, hi = 256 + 4 * lane;
    int b0 = lane & 1, b1 = lane & 2;

    const float* qk = ws + WS_QK;
    float qr[4][8];
#pragma unroll
    for (int j = 0; j < 4; ++j) {
        int h = 4 * g + j;
        float4 a = *(const float4*)(qk + h * C_ + lo);
        float4 bb = *(const float4*)(qk + h * C_ + hi);
        qr[j][0] = a.x;  qr[j][1] = a.y;  qr[j][2] = a.z;  qr[j][3] = a.w;
        qr[j][4] = bb.x; qr[j][5] = bb.y; qr[j][6] = bb.z; qr[j][7] = bb.w;
    }

    float acc[4][8];
#pragma unroll
    for (int j = 0; j < 4; ++j)
#pragma unroll
        for (int c = 0; c < 8; ++c) acc[j][c] = 0.f;
    float lsum = 0.f;

    // single-row body; fold mapping identical to round 4 (correctness-verified)
    auto row_body = [&](float4 v0, float4 v1) {
        float xv[8] = {v0.x, v0.y, v0.z, v0.w, v1.x, v1.y, v1.z, v1.w};
        float p[4];
#pragma unroll
        for (int j = 0; j < 4; ++j) {
            float s = xv[0] * qr[j][0];
#pragma unroll
            for (int c = 1; c < 8; ++c) s = fmaf(xv[c], qr[j][c], s);
            p[j] = s;
        }
        float t2[2];
#pragma unroll
        for (int i = 0; i < 2; ++i) {
            float send = b0 ? p[i] : p[i + 2];
            float recv = __shfl_xor(send, 1, 64);
            t2[i] = (b0 ? p[i + 2] : p[i]) + recv;
        }
        float u;
        {
            float send = b1 ? t2[0] : t2[1];
            float recv = __shfl_xor(send, 2, 64);
            u = (b1 ? t2[1] : t2[0]) + recv;
        }
        u += __shfl_xor(u, 4, 64);
        u += __shfl_xor(u, 8, 64);
        u += __shfl_xor(u, 16, 64);
        u += __shfl_xor(u, 32, 64);
        float e = __expf(u);  // logits O(1): un-normalized softmax safe
        lsum += e;
#pragma unroll
        for (int j = 0; j < 4; ++j) {
            int src = (j >> 1) | ((j & 1) << 1);
            float wf = __int_as_float(__builtin_amdgcn_readlane(__float_as_int(e), src));
#pragma unroll
            for (int c = 0; c < 8; ++c)
                acc[j][c] = fmaf(wf, xv[c], acc[j][c]);
        }
    };

    // prologue: stage tile 0 into xt[0] (wave w stages rows 4w..4w+3)
    {
        float4 st[4][2];
#pragma unroll
        for (int k = 0; k < 4; ++k) {
            int r = 4 * wave + k;
            st[k][0] = *(const float4*)(xp + (size_t)r * C_ + lo);
            st[k][1] = *(const float4*)(xp + (size_t)r * C_ + hi);
        }
#pragma unroll
        for (int k = 0; k < 4; ++k) {
            int r = 4 * wave + k;
            *(float4*)&xt[0][r * C_ + lo] = st[k][0];
            *(float4*)&xt[0][r * C_ + hi] = st[k][1];
        }
        __syncthreads();
    }

#pragma unroll 1
    for (int T = 0; T < nt; ++T) {
        int cur = T & 1, nxt = cur ^ 1;
        bool pf = (T + 1 < nt);
        // issue next tile's global loads early (latency hides under compute)
        float4 st[4][2];
        if (pf) {
#pragma unroll
            for (int k = 0; k < 4; ++k) {
                int r = (T + 1) * TILE_R + 4 * wave + k;
                st[k][0] = *(const float4*)(xp + (size_t)r * C_ + lo);
                st[k][1] = *(const float4*)(xp + (size_t)r * C_ + hi);
            }
        }
        // compute this wave's 8 rows (parity par) from xt[cur]
#pragma unroll 2
        for (int k = 0; k < 8; ++k) {
            int r = 2 * k + par;
            float4 v0 = *(const float4*)&xt[cur][r * C_ + lo];
            float4 v1 = *(const float4*)&xt[cur][r * C_ + hi];
            row_body(v0, v1);
        }
        // write next tile into the other buffer (safe: its readers finished
        // before the barrier that ended iteration T-1)
        if (pf) {
#pragma unroll
            for (int k = 0; k < 4; ++k) {
                int r = 4 * wave + k;
                *(float4*)&xt[nxt][r * C_ + lo] = st[k][0];
                *(float4*)&xt[nxt][r * C_ + hi] = st[k][1];
            }
        }
        __syncthreads();
    }

    // per-wave l values for its 4 heads (wave-uniform)
    float lw[4];
#pragma unroll
    for (int j = 0; j < 4; ++j) {
        int src = (j >> 1) | ((j & 1) << 1);
        lw[j] = __int_as_float(__builtin_amdgcn_readlane(__float_as_int(lsum), src));
    }

    // block-combine: reuse xt[0] as sacc (8x512 = 16KB). Two phases:
    // waves with par==0 write their head rows, then par==1 waves add.
    float* sacc = &xt[0][0];
    if (par == 0) {
#pragma unroll
        for (int j = 0; j < 4; ++j) {
            int h = 4 * g + j;
            float4 vlo = {acc[j][0], acc[j][1], acc[j][2], acc[j][3]};
            float4 vhi = {acc[j][4], acc[j][5], acc[j][6], acc[j][7]};
            *(float4*)&sacc[h * C_ + lo] = vlo;
            *(float4*)&sacc[h * C_ + hi] = vhi;
        }
        if (lane == 0) {
#pragma unroll
            for (int j = 0; j < 4; ++j) sl[4 * g + j] = lw[j];
        }
    }
    __syncthreads();
    if (par == 1) {
#pragma unroll
        for (int j = 0; j < 4; ++j) {
            int h = 4 * g + j;
            float4* d0 = (float4*)&sacc[h * C_ + lo];
            float4* d1 = (float4*)&sacc[h * C_ + hi];
            float4 a0 = d0[0], a1 = d1[0];
            a0.x += acc[j][0]; a0.y += acc[j][1]; a0.z += acc[j][2]; a0.w += acc[j][3];
            a1.x += acc[j][4]; a1.y += acc[j][5]; a1.z += acc[j][6]; a1.w += acc[j][7];
            d0[0] = a0; d1[0] = a1;
        }
        if (lane == 0) {
#pragma unroll
            for (int j = 0; j < 4; ++j) sl[4 * g + j] += lw[j];
        }
    }
    __syncthreads();

    float* pb = part + (size_t)blk * 4104;
    if (threadIdx.x < 8) pb[threadIdx.x] = sl[threadIdx.x];
    float* pa = pb + 8;
    for (int k = threadIdx.x; k < 4096; k += 256) pa[k] = sacc[k];
}

// ---------------- K4: reduce partials -> aa (unnormalized), Linv ----------------
__global__ void k_reduce(const float* __restrict__ part, float* __restrict__ ws, int CH) {
    int b = blockIdx.x >> 4, cc = blockIdx.x & 15, t = threadIdx.x;
    int h = t >> 5, c = cc * 32 + (t & 31);
    const float* pb = part + (size_t)b * CH * 4104;
    float s = 0.f;
    for (int p = 0; p < CH; ++p) s += pb[(size_t)p * 4104 + 8 + h * C_ + c];
    ws[WS_AA + b * 4096 + h * C_ + c] = s;
    if (cc == 0 && t < 8) {
        float ls = 0.f;
        for (int p = 0; p < CH; ++p) ls += pb[(size_t)p * 4104 + t];
        ws[WS_LINV + b * 8 + t] = 1.f / ls;
    }
}

// ---------------- K5: pooled (c-split halves) = Linv * aa @ Wv ----------------
__global__ void k_proj1(const float* __restrict__ ws, const float* __restrict__ Wv,
                        float* __restrict__ pp) {
    int gid = blockIdx.x * 256 + threadIdx.x;  // [0, 16384)
    int half = gid >> 13;
    int r = gid & 8191;
    int b = r >> 9, o = r & 511, h = o >> 6;
    const float* aa = ws + WS_AA + b * 4096 + h * C_;
    float Li = ws[WS_LINV + b * 8 + h];
    int c0 = half * 256;
    float s = 0.f;
#pragma unroll 8
    for (int c = 0; c < 256; ++c)
        s = fmaf(aa[c0 + c], Wv[(size_t)(c0 + c) * C_ + o], s);
    pp[half * 8192 + r] = s * Li;
}

// ---------------- K6: out = pooled @ Wp + bp ----------------
__global__ void k_proj2(const float* __restrict__ ws, const float* __restrict__ Wp,
                        const float* __restrict__ bp, float* __restrict__ out) {
    int gid = blockIdx.x * 256 + threadIdx.x;  // [0, 8192)
    int b = gid >> 9, o = gid & 511;
    const float* pp = ws + WS_PP + b * 512;
    float s = bp[o];
#pragma unroll 8
    for (int c = 0; c < 512; ++c) {
        float pc = pp[c] + pp[8192 + c];
        s = fmaf(pc, Wp[(size_t)c * C_ + o], s);
    }
    out[(size_t)b * C_ + o] = s;
}

extern "C" void kernel_launch(void* const* d_in, const int* in_sizes, int n_in,
                              void* d_out, int out_size, void* d_ws, size_t ws_size,
                              hipStream_t stream) {
    const float* x   = (const float*)d_in[0];
    const float* cls = (const float*)d_in[1];
    const float* Wq  = (const float*)d_in[2];
    const float* Wk  = (const float*)d_in[3];
    const float* Wv  = (const float*)d_in[4];
    const float* Wp  = (const float*)d_in[5];
    const float* bp  = (const float*)d_in[6];
    float* out = (float*)d_out;
    float* ws  = (float*)d_ws;

    int CH = CH_;
    while (CH > 1 && (size_t)(WS_PART + (size_t)B_ * CH * 4104) * 4 > ws_size) CH >>= 1;

    k_qfull<<<8, 256, 0, stream>>>(cls, Wq, ws);
    k_qk<<<64, 256, 0, stream>>>(Wk, ws);
    k_main<<<B_ * CH, 256, 0, stream>>>(x, ws, ws + WS_PART, CH);
    k_reduce<<<B_ * 16, 256, 0, stream>>>(ws + WS_PART, ws, CH);
    k_proj1<<<64, 256, 0, stream>>>(ws, Wv, ws + WS_PP);
    k_proj2<<<32, 256, 0, stream>>>(ws, Wp, bp, out);
}

// Round 6
// 221.924 us; speedup vs baseline: 1.0654x; 1.0654x over previous
//
#include <hip/hip_runtime.h>
#include <hip/hip_bf16.h>

#define B_ 16
#define N_ 8192
#define C_ 512
#define H_ 8
#define CH_ 32

typedef __attribute__((ext_vector_type(8))) short bf16x8;
typedef __attribute__((ext_vector_type(4))) float f32x4;

// ws float layout:
//   [0, 512)          qfull (cls@Wq * scale)
//   [512, 4608)       qk[h][c]  (8 x 512) fp32
//   [4608, 8704)      qkb: MFMA A-fragments, 16 steps x 64 lanes x 16B (bf16)
//   [8704, 8832)      Linv[b][h]
//   [8832, 74368)     aa[b][h][c] (16 x 8 x 512)
//   [74368, 90752)    pp[half][b][o] (2 x 16 x 512)
//   [90752, ...)      partials per (b,chunk): { l[8], acc[8*512] } stride 4104
#define WS_QK   512
#define WS_QKB  4608
#define WS_LINV 8704
#define WS_AA   8832
#define WS_PP   74368
#define WS_PART 90752

static __device__ __forceinline__ unsigned pk2(float a, float b) {
    // two fp32 -> packed bf16 pair (RNE), a in low half
    unsigned ua = __float_as_uint(a), ub = __float_as_uint(b);
    unsigned ra = (ua + 0x7fffu + ((ua >> 16) & 1u)) >> 16;
    unsigned rb = (ub + 0x7fffu + ((ub >> 16) & 1u)) & 0xffff0000u;
    return ra | rb;
}

// ---------------- K1: qfull = cls @ Wq * HD^-0.5 ----------------
__global__ void k_qfull(const float* __restrict__ cls, const float* __restrict__ Wq,
                        float* __restrict__ ws) {
    __shared__ float red[256];
    int t = threadIdx.x;
    int o = blockIdx.x * 64 + (t & 63);
    int q = t >> 6;
    float p = 0.f;
    for (int c = q * 128; c < q * 128 + 128; ++c)
        p += cls[c] * Wq[c * C_ + o];
    red[t] = p;
    __syncthreads();
    if (t < 64) {
        float s = red[t] + red[t + 64] + red[t + 128] + red[t + 192];
        ws[o] = s * 0.125f;
    }
}

// ---------------- K2: qk[h][c] = sum_d Wk[c, h*64+d] * qfull[h*64+d] ----------------
__global__ void k_qk(const float* __restrict__ Wk, float* __restrict__ ws) {
    __shared__ float wrow[8 * 520];
    __shared__ float qf[512];
    int t = threadIdx.x;
    int c0 = blockIdx.x * 8;
    int r = t >> 5;
    int col = (t & 31) * 16;
    const float4* src = (const float4*)(Wk + (size_t)(c0 + r) * C_ + col);
    float4* dst = (float4*)(&wrow[r * 520 + col]);
    dst[0] = src[0]; dst[1] = src[1]; dst[2] = src[2]; dst[3] = src[3];
    if (t < 128) ((float4*)qf)[t] = ((const float4*)ws)[t];
    __syncthreads();
    if (t < 64) {
        int h = t >> 3, cc = t & 7;
        const float* wr = &wrow[cc * 520 + h * 64];
        const float* qh = &qf[h * 64];
        float s = 0.f;
#pragma unroll
        for (int d = 0; d < 64; ++d) s += wr[d] * qh[d];
        ws[WS_QK + h * C_ + c0 + cc] = s;
    }
}

// ---------------- K2b: pack qk into MFMA A-fragment layout (bf16) ----------------
// A for D = qk(16x32-step) . x^T : lane l holds A[row=l&15][k=(l>>4)*8+j], j=0..7.
// rows 8..15 zero-padded (only 8 real heads).
__global__ void k_qkb(float* __restrict__ ws) {
    int l = threadIdx.x;  // 64 threads
    int h = l & 15;
    const float* qk = ws + WS_QK;
    uint4* dst = (uint4*)(ws + WS_QKB);
    for (int s = 0; s < 16; ++s) {
        float v[8];
#pragma unroll
        for (int j = 0; j < 8; ++j) {
            int k = s * 32 + ((l >> 4) << 3) + j;
            v[j] = (h < H_) ? qk[h * C_ + k] : 0.f;
        }
        uint4 o;
        o.x = pk2(v[0], v[1]); o.y = pk2(v[2], v[3]);
        o.z = pk2(v[4], v[5]); o.w = pk2(v[6], v[7]);
        dst[s * 64 + l] = o;
    }
}

// ---------------- K3: main streaming pass (MFMA logits, round 6) ----------------
// Per block: 256 rows. Wave w handles tiles {w, w+4, w+8, w+12} (16 rows each),
// staged into its private 16KB LDS slot as bf16, XOR-swizzled:
//   slot16B[r*64 + (c16 ^ (r&7))] = row r, cols [8*c16, 8*c16+8)
// QK: D[h, r] = sum_s A(qkb) . B(x^T); D layout: lane l = logits of x-row
// (l&15) for heads 4*(l>>4)+reg. exp -> PV weights read via readlane from
// lanes r (heads 0-3) and r+16 (heads 4-7). PV: plain FMA, lane owns cols
// [8*lane, 8*lane+8). No per-row cross-lane chains anywhere.
__global__ __launch_bounds__(256) void k_main(const float* __restrict__ x,
                                              const float* __restrict__ ws,
                                              float* __restrict__ part, int CH) {
    __shared__ uint4 xt[4][1024];   // 4 waves x 16 KB
    __shared__ float sl4[4][8];

    int blk = blockIdx.x;
    int b = blk / CH, chunk = blk % CH;
    int lane = threadIdx.x & 63, wave = threadIdx.x >> 6;
    int rpb = N_ / CH;              // 256
    int n0 = chunk * rpb;
    const float* xp = x + ((size_t)b * N_ + n0) * C_;

    const uint4* qkb = (const uint4*)(ws + WS_QKB);
    uint4* slot = &xt[wave][0];

    float acc[8][8];
#pragma unroll
    for (int h = 0; h < 8; ++h)
#pragma unroll
        for (int c = 0; c < 8; ++c) acc[h][c] = 0.f;
    float lt[4] = {0.f, 0.f, 0.f, 0.f};

#pragma unroll 1
    for (int ti = 0; ti < 4; ++ti) {
        int row0 = (ti * 4 + wave) * 16;
        const float* xr = xp + (size_t)row0 * C_ + 8 * lane;

        // ---- stage 16 rows (fp32 global -> bf16 LDS), two 8-row chunks ----
#pragma unroll
        for (int hf = 0; hf < 2; ++hf) {
            float4 L0[8], L1[8];
#pragma unroll
            for (int r8 = 0; r8 < 8; ++r8) {
                const float4* src = (const float4*)(xr + (size_t)(hf * 8 + r8) * C_);
                L0[r8] = src[0]; L1[r8] = src[1];
            }
#pragma unroll
            for (int r8 = 0; r8 < 8; ++r8) {
                int r = hf * 8 + r8;
                uint4 o;
                o.x = pk2(L0[r8].x, L0[r8].y);
                o.y = pk2(L0[r8].z, L0[r8].w);
                o.z = pk2(L1[r8].x, L1[r8].y);
                o.w = pk2(L1[r8].z, L1[r8].w);
                slot[r * 64 + (lane ^ (r & 7))] = o;
            }
        }
        __syncthreads();  // drain ds_writes (cross-lane visibility within wave)

        // ---- QK: one MFMA chain over K=512 (16 steps) ----
        f32x4 D = {0.f, 0.f, 0.f, 0.f};
        int rql = lane & 15;
#pragma unroll
        for (int s = 0; s < 16; ++s) {
            uint4 a = qkb[s * 64 + lane];
            uint4 bx = slot[rql * 64 + ((s * 4 + (lane >> 4)) ^ (lane & 7))];
            D = __builtin_amdgcn_mfma_f32_16x16x32_bf16(
                    *(bf16x8*)&a, *(bf16x8*)&bx, D, 0, 0, 0);
        }
        float e[4];
#pragma unroll
        for (int j = 0; j < 4; ++j) { e[j] = __expf(D[j]); lt[j] += e[j]; }

        // ---- PV: 16 rows, weights broadcast via readlane ----
#pragma unroll
        for (int r = 0; r < 16; ++r) {
            uint4 xv = slot[r * 64 + (lane ^ (r & 7))];
            float w[8];
#pragma unroll
            for (int j = 0; j < 4; ++j) {
                w[j]     = __int_as_float(__builtin_amdgcn_readlane(__float_as_int(e[j]), r));
                w[4 + j] = __int_as_float(__builtin_amdgcn_readlane(__float_as_int(e[j]), 16 + r));
            }
            unsigned dw[4] = {xv.x, xv.y, xv.z, xv.w};
            float xf[8];
#pragma unroll
            for (int q = 0; q < 4; ++q) {
                xf[2 * q]     = __uint_as_float(dw[q] << 16);
                xf[2 * q + 1] = __uint_as_float(dw[q] & 0xffff0000u);
            }
#pragma unroll
            for (int h = 0; h < 8; ++h)
#pragma unroll
                for (int c = 0; c < 8; ++c)
                    acc[h][c] = fmaf(w[h], xf[c], acc[h][c]);
        }
        __syncthreads();  // all reads of slot done before next tile's stage
    }

    // ---- block combine: each wave dumps acc into its own slot (plain layout) ----
    float* sf = (float*)slot;
#pragma unroll
    for (int h = 0; h < 8; ++h) {
        float4 v0 = {acc[h][0], acc[h][1], acc[h][2], acc[h][3]};
        float4 v1 = {acc[h][4], acc[h][5], acc[h][6], acc[h][7]};
        *(float4*)&sf[h * C_ + 8 * lane] = v0;
        *(float4*)&sf[h * C_ + 8 * lane + 4] = v1;
    }
    // l[h]: reduce lt over the 16 lanes of each group
#pragma unroll
    for (int j = 0; j < 4; ++j) {
        lt[j] += __shfl_xor(lt[j], 1, 64);
        lt[j] += __shfl_xor(lt[j], 2, 64);
        lt[j] += __shfl_xor(lt[j], 4, 64);
        lt[j] += __shfl_xor(lt[j], 8, 64);
    }
    int g = lane >> 4;
    if ((lane & 15) == 0 && g < 2) {
#pragma unroll
        for (int j = 0; j < 4; ++j) sl4[wave][4 * g + j] = lt[j];
    }
    __syncthreads();

    float* pb = part + (size_t)blk * 4104;
    if (threadIdx.x < 8)
        pb[threadIdx.x] = sl4[0][threadIdx.x] + sl4[1][threadIdx.x] +
                          sl4[2][threadIdx.x] + sl4[3][threadIdx.x];
    const float* s0 = (const float*)&xt[0][0];
    const float* s1 = (const float*)&xt[1][0];
    const float* s2 = (const float*)&xt[2][0];
    const float* s3 = (const float*)&xt[3][0];
    float* pa = pb + 8;
    for (int k = threadIdx.x; k < 4096; k += 256)
        pa[k] = s0[k] + s1[k] + s2[k] + s3[k];
}

// ---------------- K4: reduce partials -> aa (unnormalized), Linv ----------------
__global__ void k_reduce(const float* __restrict__ part, float* __restrict__ ws, int CH) {
    int b = blockIdx.x >> 4, cc = blockIdx.x & 15, t = threadIdx.x;
    int h = t >> 5, c = cc * 32 + (t & 31);
    const float* pb = part + (size_t)b * CH * 4104;
    float s = 0.f;
    for (int p = 0; p < CH; ++p) s += pb[(size_t)p * 4104 + 8 + h * C_ + c];
    ws[WS_AA + b * 4096 + h * C_ + c] = s;
    if (cc == 0 && t < 8) {
        float ls = 0.f;
        for (int p = 0; p < CH; ++p) ls += pb[(size_t)p * 4104 + t];
        ws[WS_LINV + b * 8 + t] = 1.f / ls;
    }
}

// ---------------- K5: pooled (c-split halves) = Linv * aa @ Wv ----------------
__global__ void k_proj1(const float* __restrict__ ws, const float* __restrict__ Wv,
                        float* __restrict__ pp) {
    int gid = blockIdx.x * 256 + threadIdx.x;  // [0, 16384)
    int half = gid >> 13;
    int r = gid & 8191;
    int b = r >> 9, o = r & 511, h = o >> 6;
    const float* aa = ws + WS_AA + b * 4096 + h * C_;
    float Li = ws[WS_LINV + b * 8 + h];
    int c0 = half * 256;
    float s = 0.f;
#pragma unroll 8
    for (int c = 0; c < 256; ++c)
        s = fmaf(aa[c0 + c], Wv[(size_t)(c0 + c) * C_ + o], s);
    pp[half * 8192 + r] = s * Li;
}

// ---------------- K6: out = pooled @ Wp + bp ----------------
__global__ void k_proj2(const float* __restrict__ ws, const float* __restrict__ Wp,
                        const float* __restrict__ bp, float* __restrict__ out) {
    int gid = blockIdx.x * 256 + threadIdx.x;  // [0, 8192)
    int b = gid >> 9, o = gid & 511;
    const float* pp = ws + WS_PP + b * 512;
    float s = bp[o];
#pragma unroll 8
    for (int c = 0; c < 512; ++c) {
        float pc = pp[c] + pp[8192 + c];
        s = fmaf(pc, Wp[(size_t)c * C_ + o], s);
    }
    out[(size_t)b * C_ + o] = s;
}

extern "C" void kernel_launch(void* const* d_in, const int* in_sizes, int n_in,
                              void* d_out, int out_size, void* d_ws, size_t ws_size,
                              hipStream_t stream) {
    const float* x   = (const float*)d_in[0];
    const float* cls = (const float*)d_in[1];
    const float* Wq  = (const float*)d_in[2];
    const float* Wk  = (const float*)d_in[3];
    const float* Wv  = (const float*)d_in[4];
    const float* Wp  = (const float*)d_in[5];
    const float* bp  = (const float*)d_in[6];
    float* out = (float*)d_out;
    float* ws  = (float*)d_ws;

    int CH = CH_;
    while (CH > 1 && (size_t)(WS_PART + (size_t)B_ * CH * 4104) * 4 > ws_size) CH >>= 1;

    k_qfull<<<8, 256, 0, stream>>>(cls, Wq, ws);
    k_qk<<<64, 256, 0, stream>>>(Wk, ws);
    k_qkb<<<1, 64, 0, stream>>>(ws);
    k_main<<<B_ * CH, 256, 0, stream>>>(x, ws, ws + WS_PART, CH);
    k_reduce<<<B_ * 16, 256, 0, stream>>>(ws + WS_PART, ws, CH);
    k_proj1<<<64, 256, 0, stream>>>(ws, Wv, ws + WS_PP);
    k_proj2<<<32, 256, 0, stream>>>(ws, Wp, bp, out);
}

// Round 7
// 120.147 us; speedup vs baseline: 1.9680x; 1.8471x over previous
//
#include <hip/hip_runtime.h>
#include <hip/hip_bf16.h>

#define B_ 16
#define N_ 8192
#define C_ 512
#define H_ 8
#define HD_ 64
#define CH_ 32

// ws float layout:
//   [0, 512)          qfull (cls@Wq * scale)
//   [512, 4608)       qk[h][c]  (8 x 512)
//   [4608, 4736)      Linv[b][h]  (16 x 8)
//   [4736, 70272)     aa[b][h][c] unnormalized weighted sums (16 x 8 x 512)
//   [70272, 86656)    pp[half][b][o] partial pooled (2 x 16 x 512)
//   [86656, ...)      partials: per (b,chunk): { l[8], acc[8*512] } stride 4104
#define WS_QK   512
#define WS_LINV 4608
#define WS_AA   4736
#define WS_PP   70272
#define WS_PART 86656

// Round-7 theory: the hidden cost everywhere was un-unrolled load->use loops
// (one s_waitcnt vmcnt(0) per element, ~300-900 cyc each). R1->R2's -79us came
// from exactly this fix on the old k_merge. Apply the lens to every kernel.

// ---------------- K1: qfull = cls @ Wq * HD^-0.5 ----------------
__global__ void k_qfull(const float* __restrict__ cls, const float* __restrict__ Wq,
                        float* __restrict__ ws) {
    __shared__ float red[256];
    int t = threadIdx.x;
    int o = blockIdx.x * 64 + (t & 63);
    int q = t >> 6;  // 0..3
    float p = 0.f;
#pragma unroll 16
    for (int c = q * 128; c < q * 128 + 128; ++c)
        p += cls[c] * Wq[c * C_ + o];
    red[t] = p;
    __syncthreads();
    if (t < 64) {
        float s = red[t] + red[t + 64] + red[t + 128] + red[t + 192];
        ws[o] = s * 0.125f;  // HD^-0.5 = 1/8
    }
}

// ---------------- K2: qk[h][c] = sum_d Wk[c, h*64+d] * qfull[h*64+d] ----------------
__global__ void k_qk(const float* __restrict__ Wk, float* __restrict__ ws) {
    __shared__ float wrow[8 * 520];  // 8 rows of Wk, padded stride
    __shared__ float qf[512];
    int t = threadIdx.x;
    int c0 = blockIdx.x * 8;
    int r = t >> 5;             // 8 rows, 32 threads each
    int col = (t & 31) * 16;    // 16 floats per thread
    const float4* src = (const float4*)(Wk + (size_t)(c0 + r) * C_ + col);
    float4* dst = (float4*)(&wrow[r * 520 + col]);
    dst[0] = src[0]; dst[1] = src[1]; dst[2] = src[2]; dst[3] = src[3];
    if (t < 128) ((float4*)qf)[t] = ((const float4*)ws)[t];
    __syncthreads();
    if (t < 64) {
        int h = t >> 3, cc = t & 7;
        const float* wr = &wrow[cc * 520 + h * 64];
        const float* qh = &qf[h * 64];
        float s = 0.f;
#pragma unroll
        for (int d = 0; d < 64; ++d) s += wr[d] * qh[d];
        ws[WS_QK + h * C_ + c0 + cc] = s;
    }
}

// ---------------- K3: main streaming pass over x (R3 structure, best measured) ----------------
__global__ __launch_bounds__(256) void k_main(const float* __restrict__ x,
                                              const float* __restrict__ ws,
                                              float* __restrict__ part, int CH) {
    int blk = blockIdx.x;
    int b = blk / CH, chunk = blk % CH;
    int lane = threadIdx.x & 63, wave = threadIdx.x >> 6;
    int rpb = N_ / CH;       // rows per block
    int rpw = rpb >> 2;      // rows per wave (4 waves) = 64
    int n0 = chunk * rpb + wave * rpw;

    const float* qk = ws + WS_QK;
    float qr[8][8];
#pragma unroll
    for (int h = 0; h < 8; ++h) {
        float4 a = *(const float4*)(qk + h * C_ + 4 * lane);
        float4 bb = *(const float4*)(qk + h * C_ + 256 + 4 * lane);
        qr[h][0] = a.x;  qr[h][1] = a.y;  qr[h][2] = a.z;  qr[h][3] = a.w;
        qr[h][4] = bb.x; qr[h][5] = bb.y; qr[h][6] = bb.z; qr[h][7] = bb.w;
    }

    float acc[8][8];
#pragma unroll
    for (int h = 0; h < 8; ++h)
#pragma unroll
        for (int j = 0; j < 8; ++j) acc[h][j] = 0.f;
    float lsum = 0.f;

    const float* xp = x + ((size_t)b * N_ + n0) * C_;
    int lo = 4 * lane, hi = 256 + 4 * lane;

    auto row_body = [&](const float4& v0, const float4& v1) {
        float xv[8] = {v0.x, v0.y, v0.z, v0.w, v1.x, v1.y, v1.z, v1.w};
        float p[8];
#pragma unroll
        for (int h = 0; h < 8; ++h) {
            float s = xv[0] * qr[h][0];
#pragma unroll
            for (int j = 1; j < 8; ++j) s = fmaf(xv[j], qr[h][j], s);
            p[h] = s;
        }
        int b0 = lane & 1, b1 = lane & 2, b2 = lane & 4;
        float t4[4];
#pragma unroll
        for (int i = 0; i < 4; ++i) {
            float send = b0 ? p[i] : p[i + 4];
            float recv = __shfl_xor(send, 1, 64);
            t4[i] = (b0 ? p[i + 4] : p[i]) + recv;
        }
        float u2[2];
#pragma unroll
        for (int i = 0; i < 2; ++i) {
            float send = b1 ? t4[i] : t4[i + 2];
            float recv = __shfl_xor(send, 2, 64);
            u2[i] = (b1 ? t4[i + 2] : t4[i]) + recv;
        }
        float send = b2 ? u2[0] : u2[1];
        float recv = __shfl_xor(send, 4, 64);
        float v = (b2 ? u2[1] : u2[0]) + recv;
        v += __shfl_xor(v, 8, 64);
        v += __shfl_xor(v, 16, 64);
        v += __shfl_xor(v, 32, 64);
        float e = __expf(v);   // logits ~N(0,0.2): un-normalized softmax is safe
        lsum += e;
#pragma unroll
        for (int h = 0; h < 8; ++h) {
            int src = ((h & 4) >> 2) | (h & 2) | ((h & 1) << 2);
            float wf = __int_as_float(__builtin_amdgcn_readlane(__float_as_int(e), src));
#pragma unroll
            for (int j = 0; j < 8; ++j) acc[h][j] = fmaf(wf, xv[j], acc[h][j]);
        }
    };

    // prefetch depth 8 (16 KB in flight per wave)
    float4 R[8][2];
#pragma unroll
    for (int k = 0; k < 8; ++k) {
        R[k][0] = *(const float4*)(xp + (size_t)k * C_ + lo);
        R[k][1] = *(const float4*)(xp + (size_t)k * C_ + hi);
    }
#pragma unroll 1
    for (int i = 0; i < rpw; i += 8) {
#pragma unroll
        for (int k = 0; k < 8; ++k) {
            float4 v0 = R[k][0], v1 = R[k][1];
            int nf = i + k + 8; nf = nf < rpw ? nf : rpw - 1;  // clamped prefetch
            R[k][0] = *(const float4*)(xp + (size_t)nf * C_ + lo);
            R[k][1] = *(const float4*)(xp + (size_t)nf * C_ + hi);
            row_body(v0, v1);
        }
    }

    // per-wave l values (uniform), then block-combine in LDS
    float lw[8];
#pragma unroll
    for (int h = 0; h < 8; ++h) {
        int src = ((h & 4) >> 2) | (h & 2) | ((h & 1) << 2);
        lw[h] = __int_as_float(__builtin_amdgcn_readlane(__float_as_int(lsum), src));
    }

    __shared__ float sacc[8 * 512];
    __shared__ float sl[8];
    for (int w = 0; w < 4; ++w) {
        if (wave == w) {
#pragma unroll
            for (int h = 0; h < 8; ++h) {
                float4 vlo = {acc[h][0], acc[h][1], acc[h][2], acc[h][3]};
                float4 vhi = {acc[h][4], acc[h][5], acc[h][6], acc[h][7]};
                float4* d0 = (float4*)&sacc[h * C_ + lo];
                float4* d1 = (float4*)&sacc[h * C_ + hi];
                if (w == 0) { d0[0] = vlo; d1[0] = vhi; }
                else {
                    float4 a0 = d0[0], a1 = d1[0];
                    a0.x += vlo.x; a0.y += vlo.y; a0.z += vlo.z; a0.w += vlo.w;
                    a1.x += vhi.x; a1.y += vhi.y; a1.z += vhi.z; a1.w += vhi.w;
                    d0[0] = a0; d1[0] = a1;
                }
            }
            if (lane == 0) {
#pragma unroll
                for (int h = 0; h < 8; ++h) {
                    if (w == 0) sl[h] = lw[h]; else sl[h] += lw[h];
                }
            }
        }
        __syncthreads();
    }

    float* pb = part + (size_t)blk * 4104;
    if (threadIdx.x < 8) pb[threadIdx.x] = sl[threadIdx.x];
    float* pa = pb + 8;
    for (int k = threadIdx.x; k < 4096; k += 256) pa[k] = sacc[k];
}

// ---------------- K4: reduce partials -> aa (unnormalized), Linv ----------------
__global__ void k_reduce(const float* __restrict__ part, float* __restrict__ ws, int CH) {
    int b = blockIdx.x >> 4, cc = blockIdx.x & 15, t = threadIdx.x;
    int h = t >> 5, c = cc * 32 + (t & 31);
    const float* pb = part + (size_t)b * CH * 4104;
    float s = 0.f;
#pragma unroll 8
    for (int p = 0; p < CH; ++p) s += pb[(size_t)p * 4104 + 8 + h * C_ + c];
    ws[WS_AA + b * 4096 + h * C_ + c] = s;
    if (cc == 0 && t < 8) {
        float ls = 0.f;
#pragma unroll 8
        for (int p = 0; p < CH; ++p) ls += pb[(size_t)p * 4104 + t];
        ws[WS_LINV + b * 8 + t] = 1.f / ls;
    }
}

// ---------------- K5: pooled (c-split halves) = Linv * aa @ Wv ----------------
__global__ void k_proj1(const float* __restrict__ ws, const float* __restrict__ Wv,
                        float* __restrict__ pp) {
    int gid = blockIdx.x * 256 + threadIdx.x;  // [0, 16384)
    int half = gid >> 13;
    int r = gid & 8191;
    int b = r >> 9, o = r & 511, h = o >> 6;
    const float* aa = ws + WS_AA + b * 4096 + h * C_;
    float Li = ws[WS_LINV + b * 8 + h];
    int c0 = half * 256;
    float s = 0.f;
#pragma unroll 16
    for (int c = 0; c < 256; ++c)
        s = fmaf(aa[c0 + c], Wv[(size_t)(c0 + c) * C_ + o], s);
    pp[half * 8192 + r] = s * Li;
}

// ---------------- K6: out = pooled @ Wp + bp ----------------
__global__ void k_proj2(const float* __restrict__ ws, const float* __restrict__ Wp,
                        const float* __restrict__ bp, float* __restrict__ out) {
    int gid = blockIdx.x * 256 + threadIdx.x;  // [0, 8192)
    int b = gid >> 9, o = gid & 511;
    const float* pp = ws + WS_PP + b * 512;
    float s = bp[o];
#pragma unroll 16
    for (int c = 0; c < 512; ++c) {
        float pc = pp[c] + pp[8192 + c];
        s = fmaf(pc, Wp[(size_t)c * C_ + o], s);
    }
    out[(size_t)b * C_ + o] = s;
}

extern "C" void kernel_launch(void* const* d_in, const int* in_sizes, int n_in,
                              void* d_out, int out_size, void* d_ws, size_t ws_size,
                              hipStream_t stream) {
    const float* x   = (const float*)d_in[0];
    const float* cls = (const float*)d_in[1];
    const float* Wq  = (const float*)d_in[2];
    const float* Wk  = (const float*)d_in[3];
    const float* Wv  = (const float*)d_in[4];
    const float* Wp  = (const float*)d_in[5];
    const float* bp  = (const float*)d_in[6];
    float* out = (float*)d_out;
    float* ws  = (float*)d_ws;

    int CH = CH_;
    while (CH > 1 && (size_t)(WS_PART + (size_t)B_ * CH * 4104) * 4 > ws_size) CH >>= 1;

    k_qfull<<<8, 256, 0, stream>>>(cls, Wq, ws);
    k_qk<<<64, 256, 0, stream>>>(Wk, ws);
    k_main<<<B_ * CH, 256, 0, stream>>>(x, ws, ws + WS_PART, CH);
    k_reduce<<<B_ * 16, 256, 0, stream>>>(ws + WS_PART, ws, CH);
    k_proj1<<<64, 256, 0, stream>>>(ws, Wv, ws + WS_PP);
    k_proj2<<<32, 256, 0, stream>>>(ws, Wp, bp, out);
}